// Round 6
// baseline (468.503 us; speedup 1.0000x reference)
//
#include <hip/hip_runtime.h>
#include <hip/hip_bf16.h>

#define T_LEN 512
#define HID 50
#define NBATCH 4096
#define BB 8          // batches per block (8 -> grid 512 -> 2 blocks/CU -> 2 waves/SIMD)

using short8  = __attribute__((ext_vector_type(8))) short;
using floatx4 = __attribute__((ext_vector_type(4))) float;

__device__ __forceinline__ float sigm(float v) {
  return __builtin_amdgcn_rcpf(1.0f + __builtin_amdgcn_exp2f(-1.442695041f * v));
}
__device__ __forceinline__ float tanh_f(float v) {
  return 1.0f - 2.0f * __builtin_amdgcn_rcpf(1.0f + __builtin_amdgcn_exp2f(2.885390082f * v));
}

// A-fragment read: two ds_read_b64 from a bf16 plane laid out [m16][u64] (row=128B)
// with per-row XOR swizzle ((m&7)<<4). qbase=0 -> k in [0,32), qbase=2 -> [32,64).
__device__ __forceinline__ short8 afrag(const char* plane, int rowoff, int kg, int qbase, int xr) {
  unsigned long long a = *(const unsigned long long*)(plane + rowoff + ((((qbase + 0) * 32) + 8 * kg) ^ xr));
  unsigned long long b = *(const unsigned long long*)(plane + rowoff + ((((qbase + 1) * 32) + 8 * kg) ^ xr));
  union { unsigned long long u[2]; short8 s; } t;
  t.u[0] = a; t.u[1] = b;
  return t.s;
}

__global__ __launch_bounds__(256, 2)
void gru_mfma_kernel(const float* __restrict__ x,
                     const float* __restrict__ W_ih,
                     const float* __restrict__ W_hh,
                     const float* __restrict__ b_ih,
                     const float* __restrict__ b_hh,
                     const float* __restrict__ W_fc,
                     const float* __restrict__ b_fc,
                     float* __restrict__ out) {
  // LDS map (bytes): [0,6144)      x-chunk [t64][c3][m8] f32
  //                  [6144,10240)  h buf0 (hi plane 2048 + lo plane 2048), bf16 [m16][u64] XOR-swizzled
  //                  [10240,14336) h buf1
  __shared__ alignas(16) unsigned char lds[14336];
  char* xs   = (char*)lds;
  char* hbuf = (char*)lds + 6144;

  const int tid  = threadIdx.x;
  const int lane = tid & 63;
  const int w    = tid >> 6;          // wave id: owns units 16w..16w+15
  const int ucol = lane & 15;         // N-col within tile / A-row batch index
  const int kg   = lane >> 4;         // k-group for A/B frags; m-group for C rows
  const int b0   = blockIdx.x * BB;
  const int u    = 16 * w + ucol;     // this lane's hidden unit
  const bool uv  = (u < HID);

  // ---- per-lane bias / input-weight constants (zero-guarded for pad units) ----
  const float c_r  = uv ? (b_ih[u] + b_hh[u]) : 0.f;
  const float c_z  = uv ? (b_ih[50 + u] + b_hh[50 + u]) : 0.f;
  const float c_ni = uv ? b_ih[100 + u] : 0.f;
  const float c_nh = uv ? b_hh[100 + u] : 0.f;
  float u_r[3], u_z[3], u_n[3];
#pragma unroll
  for (int c = 0; c < 3; ++c) {
    u_r[c] = uv ? W_ih[u * 3 + c] : 0.f;
    u_z[c] = uv ? W_ih[(50 + u) * 3 + c] : 0.f;
    u_n[c] = uv ? W_ih[(100 + u) * 3 + c] : 0.f;
  }
  const float wfc = uv ? W_fc[u] : 0.f;

  // ---- persistent B-fragments (W_hh), bf16x2 split, built once ----
  short8 Bh[3][2], Bl[3][2];
#pragma unroll
  for (int tau = 0; tau < 3; ++tau) {
    const int row = uv ? (tau * 50 + u) : 0;
    const float* Wrow = W_hh + row * HID;
#pragma unroll
    for (int f = 0; f < 2; ++f) {
      union { short a[8]; short8 s; } ph, pl;
#pragma unroll
      for (int e = 0; e < 8; ++e) {
        const int k = 32 * f + 16 * (e >> 2) + 4 * kg + (e & 3);
        const float v = (uv && k < HID) ? Wrow[k] : 0.f;
        __hip_bfloat16 bh = __float2bfloat16(v);
        const float vh = __bfloat162float(bh);
        __hip_bfloat16 bl = __float2bfloat16(v - vh);
        ph.a[e] = *(short*)&bh;
        pl.a[e] = *(short*)&bl;
      }
      Bh[tau][f] = ph.s;
      Bl[tau][f] = pl.s;
    }
  }

  // zero h buf0 AND buf1 (2 x 4096 B)
  ((float4*)hbuf)[tid] = make_float4(0.f, 0.f, 0.f, 0.f);
  ((float4*)(hbuf + 4096))[tid] = make_float4(0.f, 0.f, 0.f, 0.f);

  float h[4] = {0.f, 0.f, 0.f, 0.f};           // unit u, batches 4*kg..4*kg+3 (kg<2 valid)

  const int arow = ucol * 128;
  const int axr  = (ucol & 7) << 4;
  const int kgc  = kg & 1;                      // x-read kg clamp (kg>=2 rows are pad)
  const floatx4 z4 = {0.f, 0.f, 0.f, 0.f};

  for (int tc = 0; tc < 8; ++tc) {
    // ---- stage x chunk: 8 batches x 64 t x 3 c -> LDS [t][c][m8] ----
    {
      const int sm = tid >> 5, seg = tid & 31;   // batch, 6-float segment
      const float* xb = x + (size_t)(b0 + sm) * (T_LEN * 3) + tc * 192 + seg * 6;
      const float2 v0 = *(const float2*)(xb + 0);
      const float2 v1 = *(const float2*)(xb + 2);
      const float2 v2 = *(const float2*)(xb + 4);
      const float vv[6] = {v0.x, v0.y, v1.x, v1.y, v2.x, v2.y};
#pragma unroll
      for (int jj = 0; jj < 6; ++jj) {
        const int i = seg * 6 + jj;
        *(float*)(xs + (i / 3) * 96 + (i % 3) * 32 + sm * 4) = vv[jj];
      }
    }
    __syncthreads();

#pragma unroll 2
    for (int s = 0; s < 64; ++s) {
      const int par = s & 1;
      const char* rp = hbuf + par * 4096;
      char*       wp = hbuf + (par ^ 1) * 4096;

      const short8 A0h = afrag(rp,        arow, kg, 0, axr);
      const short8 A1h = afrag(rp,        arow, kg, 2, axr);
      const short8 A0l = afrag(rp + 2048, arow, kg, 0, axr);
      const short8 A1l = afrag(rp + 2048, arow, kg, 2, axr);

      const float4 xv0 = *(const float4*)(xs + s * 96 + 0 * 32 + kgc * 16);
      const float4 xv1 = *(const float4*)(xs + s * 96 + 1 * 32 + kgc * 16);
      const float4 xv2 = *(const float4*)(xs + s * 96 + 2 * 32 + kgc * 16);

      floatx4 acc[3];
#pragma unroll
      for (int tau = 0; tau < 3; ++tau) {
        floatx4 a = __builtin_amdgcn_mfma_f32_16x16x32_bf16(A0h, Bh[tau][0], z4, 0, 0, 0);
        a = __builtin_amdgcn_mfma_f32_16x16x32_bf16(A0h, Bl[tau][0], a, 0, 0, 0);
        a = __builtin_amdgcn_mfma_f32_16x16x32_bf16(A0l, Bh[tau][0], a, 0, 0, 0);
        a = __builtin_amdgcn_mfma_f32_16x16x32_bf16(A1h, Bh[tau][1], a, 0, 0, 0);
        a = __builtin_amdgcn_mfma_f32_16x16x32_bf16(A1h, Bl[tau][1], a, 0, 0, 0);
        a = __builtin_amdgcn_mfma_f32_16x16x32_bf16(A1l, Bh[tau][1], a, 0, 0, 0);
        acc[tau] = a;
      }

      const float xa[4]  = {xv0.x, xv0.y, xv0.z, xv0.w};
      const float xb_[4] = {xv1.x, xv1.y, xv1.z, xv1.w};
      const float xc[4]  = {xv2.x, xv2.y, xv2.z, xv2.w};
#pragma unroll
      for (int r = 0; r < 4; ++r) {
        const float x0 = xa[r], x1 = xb_[r], x2 = xc[r];
        const float gr = fmaf(x0, u_r[0], fmaf(x1, u_r[1], fmaf(x2, u_r[2], c_r)));
        const float gz = fmaf(x0, u_z[0], fmaf(x1, u_z[1], fmaf(x2, u_z[2], c_z)));
        const float gn = fmaf(x0, u_n[0], fmaf(x1, u_n[1], fmaf(x2, u_n[2], c_ni)));
        const float rr = sigm(acc[0][r] + gr);
        const float zz = sigm(acc[1][r] + gz);
        const float nv = gn + rr * (acc[2][r] + c_nh);
        const float nn = tanh_f(nv);
        const float hn = nn + zz * (h[r] - nn);
        h[r] = hn;
        if (kg < 2) {                            // rows 8..15 are pad: skip stores
          __hip_bfloat16 bh = __float2bfloat16(hn);
          const float fh = __bfloat162float(bh);
          __hip_bfloat16 bl = __float2bfloat16(hn - fh);
          const int mrow = 4 * kg + r;
          const int off  = mrow * 128 + ((2 * u) ^ ((mrow & 7) << 4));
          *(short*)(wp + off)        = *(short*)&bh;
          *(short*)(wp + 2048 + off) = *(short*)&bl;
        }
      }
      __syncthreads();
    }
  }

  // ---- FC epilogue: out[b] = sum_u h_u * W_fc[u] + b_fc ----
  float p[4];
#pragma unroll
  for (int r = 0; r < 4; ++r) p[r] = h[r] * wfc;
#pragma unroll
  for (int mask = 1; mask < 16; mask <<= 1) {
#pragma unroll
    for (int r = 0; r < 4; ++r) p[r] += __shfl_xor(p[r], mask);
  }
  if (ucol == 0) {
    *(float4*)(lds + (w * 16 + 4 * kg) * 4) = make_float4(p[0], p[1], p[2], p[3]);
  }
  __syncthreads();
  if (tid < BB) {
    float ssum = 0.f;
#pragma unroll
    for (int ww = 0; ww < 4; ++ww) ssum += *(const float*)(lds + (ww * 16 + tid) * 4);
    out[b0 + tid] = ssum + b_fc[0];
  }
}

extern "C" void kernel_launch(void* const* d_in, const int* in_sizes, int n_in,
                              void* d_out, int out_size, void* d_ws, size_t ws_size,
                              hipStream_t stream) {
  const float* x    = (const float*)d_in[0];
  const float* W_ih = (const float*)d_in[1];
  const float* W_hh = (const float*)d_in[2];
  const float* b_ih = (const float*)d_in[3];
  const float* b_hh = (const float*)d_in[4];
  const float* W_fc = (const float*)d_in[5];
  const float* b_fc = (const float*)d_in[6];
  float* out = (float*)d_out;

  dim3 grid(NBATCH / BB);   // 512 blocks -> 2 blocks/CU -> 2 waves/SIMD
  dim3 block(256);
  gru_mfma_kernel<<<grid, block, 0, stream>>>(x, W_ih, W_hh, b_ih, b_hh, W_fc, b_fc, out);
}

// Round 7
// 301.792 us; speedup vs baseline: 1.5524x; 1.5524x over previous
//
#include <hip/hip_runtime.h>
#include <hip/hip_bf16.h>

#define T_LEN 512
#define HID 50
#define NBATCH 4096

using short8  = __attribute__((ext_vector_type(8))) short;
using floatx4 = __attribute__((ext_vector_type(4))) float;
using uintx4  = __attribute__((ext_vector_type(4))) unsigned int;

__device__ __forceinline__ float sigm(float v) {
  return __builtin_amdgcn_rcpf(1.0f + __builtin_amdgcn_exp2f(-1.442695041f * v));
}
__device__ __forceinline__ float tanh_f(float v) {
  return 1.0f - 2.0f * __builtin_amdgcn_rcpf(1.0f + __builtin_amdgcn_exp2f(2.885390082f * v));
}

// h plane: 16 rows (m) x 64 words (u), word = hi_bf16 | lo_bf16<<16, row 256 B,
// XOR swizzle ((row&15)<<4) on the byte offset (16B-slot bijection per row).
// A-fragment (frag f): k = 32f + 16*(e>>2) + 4*kg + (e&3)  -- same bijection as B build.
__device__ __forceinline__ void afrag2(const char* plane, int rowoff, int kg, int f,
                                       int xr, short8* Ah, short8* Al) {
  const uintx4 q0 = *(const uintx4*)(plane + rowoff + ((128 * f + 16 * kg) ^ xr));
  const uintx4 q1 = *(const uintx4*)(plane + rowoff + ((128 * f + 64 + 16 * kg) ^ xr));
  union { unsigned int u[4]; short8 s; } th, tl;
  th.u[0] = __builtin_amdgcn_perm(q0.y, q0.x, 0x05040100u);
  th.u[1] = __builtin_amdgcn_perm(q0.w, q0.z, 0x05040100u);
  th.u[2] = __builtin_amdgcn_perm(q1.y, q1.x, 0x05040100u);
  th.u[3] = __builtin_amdgcn_perm(q1.w, q1.z, 0x05040100u);
  tl.u[0] = __builtin_amdgcn_perm(q0.y, q0.x, 0x07060302u);
  tl.u[1] = __builtin_amdgcn_perm(q0.w, q0.z, 0x07060302u);
  tl.u[2] = __builtin_amdgcn_perm(q1.y, q1.x, 0x07060302u);
  tl.u[3] = __builtin_amdgcn_perm(q1.w, q1.z, 0x07060302u);
  *Ah = th.s;
  *Al = tl.s;
}

__global__ __launch_bounds__(256, 1)
void gru_mfma_kernel(const float* __restrict__ x,
                     const float* __restrict__ W_ih,
                     const float* __restrict__ W_hh,
                     const float* __restrict__ b_ih,
                     const float* __restrict__ b_hh,
                     const float* __restrict__ W_fc,
                     const float* __restrict__ b_fc,
                     float* __restrict__ out) {
  // LDS: [0,12288) x-chunk [t64][c3][m16] f32 ; [12288,16384) h buf0 ; [16384,20480) h buf1
  __shared__ alignas(16) unsigned char lds[20480];
  char* xs   = (char*)lds;
  char* hbuf = (char*)lds + 12288;

  const int tid  = threadIdx.x;
  const int lane = tid & 63;
  const int w    = tid >> 6;          // wave id: owns units 16w..16w+15
  const int ucol = lane & 15;         // N-col within tile / A-row (batch) index
  const int kg   = lane >> 4;         // k-group for A/B frags; m-group for C rows
  const int b0   = blockIdx.x * 16;
  const int u    = 16 * w + ucol;     // this lane's hidden unit
  const bool uv  = (u < HID);

  // ---- per-lane bias / input-weight constants ----
  const float c_r  = uv ? (b_ih[u] + b_hh[u]) : 0.f;
  const float c_z  = uv ? (b_ih[50 + u] + b_hh[50 + u]) : 0.f;
  const float c_ni = uv ? b_ih[100 + u] : 0.f;
  const float c_nh = uv ? b_hh[100 + u] : 0.f;
  float u_r[3], u_z[3], u_n[3];
#pragma unroll
  for (int c = 0; c < 3; ++c) {
    u_r[c] = uv ? W_ih[u * 3 + c] : 0.f;
    u_z[c] = uv ? W_ih[(50 + u) * 3 + c] : 0.f;
    u_n[c] = uv ? W_ih[(100 + u) * 3 + c] : 0.f;
  }
  const float wfc = uv ? W_fc[u] : 0.f;

  // ---- persistent B-fragments (W_hh), bf16x2 split ----
  short8 Bh[3][2], Bl[3][2];
#pragma unroll
  for (int tau = 0; tau < 3; ++tau) {
    const int row = uv ? (tau * 50 + u) : 0;
    const float* Wrow = W_hh + row * HID;
#pragma unroll
    for (int f = 0; f < 2; ++f) {
      union { short a[8]; short8 s; } ph, pl;
#pragma unroll
      for (int e = 0; e < 8; ++e) {
        const int k = 32 * f + 16 * (e >> 2) + 4 * kg + (e & 3);
        const float v = (uv && k < HID) ? Wrow[k] : 0.f;
        __hip_bfloat16 bh = __float2bfloat16(v);
        const float vh = __bfloat162float(bh);
        __hip_bfloat16 bl = __float2bfloat16(v - vh);
        ph.a[e] = *(short*)&bh;
        pl.a[e] = *(short*)&bl;
      }
      Bh[tau][f] = ph.s;
      Bl[tau][f] = pl.s;
    }
  }

  // zero both h buffers (2 x 4096 B)
  ((float4*)hbuf)[tid] = make_float4(0.f, 0.f, 0.f, 0.f);
  ((float4*)(hbuf + 4096))[tid] = make_float4(0.f, 0.f, 0.f, 0.f);

  float h[4] = {0.f, 0.f, 0.f, 0.f};           // unit u, batches 4*kg..4*kg+3

  const int arow = ucol * 256;                  // A row offset (batch = ucol)
  const int axr  = (ucol & 15) << 4;            // A-read XOR (16B-slot bijection)
  const floatx4 z4 = {0.f, 0.f, 0.f, 0.f};

  for (int tc = 0; tc < 8; ++tc) {
    // ---- stage x chunk: 16 batches x 64 t x 3 c -> LDS [t][c][m] ----
    {
      const int sm = tid >> 4, seg = tid & 15;
      const float* xb = x + (size_t)(b0 + sm) * (T_LEN * 3) + tc * 192 + seg * 12;
      const float4 v0 = *(const float4*)(xb + 0);
      const float4 v1 = *(const float4*)(xb + 4);
      const float4 v2 = *(const float4*)(xb + 8);
      const float vv[12] = {v0.x, v0.y, v0.z, v0.w, v1.x, v1.y, v1.z, v1.w, v2.x, v2.y, v2.z, v2.w};
#pragma unroll
      for (int jj = 0; jj < 12; ++jj) {
        const int i = seg * 12 + jj;
        *(float*)(xs + (i / 3) * 192 + (i % 3) * 64 + sm * 4) = vv[jj];
      }
    }
    __syncthreads();

#pragma unroll 2
    for (int s = 0; s < 64; ++s) {
      const int par = s & 1;
      const char* rp = hbuf + par * 4096;
      char*       wp = hbuf + (par ^ 1) * 4096;

      // x reads first (barrier-independent of h)
      const float4 xv0 = *(const float4*)(xs + s * 192 + 0 * 64 + kg * 16);
      const float4 xv1 = *(const float4*)(xs + s * 192 + 1 * 64 + kg * 16);
      const float4 xv2 = *(const float4*)(xs + s * 192 + 2 * 64 + kg * 16);

      // A-fragments: 4 x ds_read_b128 + perm unpack (hi & lo in one pass)
      short8 A0h, A0l, A1h, A1l;
      afrag2(rp, arow, kg, 0, axr, &A0h, &A0l);
      afrag2(rp, arow, kg, 1, axr, &A1h, &A1l);

      // MFMA: two 3-deep chains per gate, merged in the epilogue
      floatx4 accA[3], accB[3];
#pragma unroll
      for (int tau = 0; tau < 3; ++tau) {
        floatx4 a = __builtin_amdgcn_mfma_f32_16x16x32_bf16(A0h, Bh[tau][0], z4, 0, 0, 0);
        a = __builtin_amdgcn_mfma_f32_16x16x32_bf16(A1h, Bh[tau][1], a, 0, 0, 0);
        a = __builtin_amdgcn_mfma_f32_16x16x32_bf16(A0l, Bh[tau][0], a, 0, 0, 0);
        accA[tau] = a;
        floatx4 b = __builtin_amdgcn_mfma_f32_16x16x32_bf16(A0h, Bl[tau][0], z4, 0, 0, 0);
        b = __builtin_amdgcn_mfma_f32_16x16x32_bf16(A1h, Bl[tau][1], b, 0, 0, 0);
        b = __builtin_amdgcn_mfma_f32_16x16x32_bf16(A1l, Bh[tau][1], b, 0, 0, 0);
        accB[tau] = b;
      }

      const float xa[4]  = {xv0.x, xv0.y, xv0.z, xv0.w};
      const float xb_[4] = {xv1.x, xv1.y, xv1.z, xv1.w};
      const float xc[4]  = {xv2.x, xv2.y, xv2.z, xv2.w};
#pragma unroll
      for (int r = 0; r < 4; ++r) {
        const float x0 = xa[r], x1 = xb_[r], x2 = xc[r];
        const float ar = accA[0][r] + accB[0][r];
        const float az = accA[1][r] + accB[1][r];
        const float an = accA[2][r] + accB[2][r];
        const float gr = fmaf(x0, u_r[0], fmaf(x1, u_r[1], fmaf(x2, u_r[2], c_r)));
        const float gz = fmaf(x0, u_z[0], fmaf(x1, u_z[1], fmaf(x2, u_z[2], c_z)));
        const float gn = fmaf(x0, u_n[0], fmaf(x1, u_n[1], fmaf(x2, u_n[2], c_ni)));
        const float rr = sigm(ar + gr);
        const float zz = sigm(az + gz);
        const float nv = gn + rr * (an + c_nh);
        const float nn = tanh_f(nv);
        const float hn = nn + zz * (h[r] - nn);
        h[r] = hn;
        // pack hi|lo bf16x2 into one u32, single ds_write_b32
        __hip_bfloat16 bh = __float2bfloat16(hn);
        const unsigned short bhb = *(const unsigned short*)&bh;
        const float fh = __uint_as_float((unsigned int)bhb << 16);
        __hip_bfloat16 bl = __float2bfloat16(hn - fh);
        const unsigned short blb = *(const unsigned short*)&bl;
        const unsigned int hw = (unsigned int)bhb | ((unsigned int)blb << 16);
        const int mrow = 4 * kg + r;
        *(unsigned int*)(wp + mrow * 256 + ((4 * u) ^ ((mrow & 15) << 4))) = hw;
      }
      __syncthreads();
    }
  }

  // ---- FC epilogue ----
  float p[4];
#pragma unroll
  for (int r = 0; r < 4; ++r) p[r] = h[r] * wfc;
#pragma unroll
  for (int mask = 1; mask < 16; mask <<= 1) {
#pragma unroll
    for (int r = 0; r < 4; ++r) p[r] += __shfl_xor(p[r], mask);
  }
  if (ucol == 0) {
    *(float4*)(lds + (w * 16 + 4 * kg) * 4) = make_float4(p[0], p[1], p[2], p[3]);
  }
  __syncthreads();
  if (tid < 16) {
    float ssum = 0.f;
#pragma unroll
    for (int ww = 0; ww < 4; ++ww) ssum += *(const float*)(lds + (ww * 16 + tid) * 4);
    out[b0 + tid] = ssum + b_fc[0];
  }
}

extern "C" void kernel_launch(void* const* d_in, const int* in_sizes, int n_in,
                              void* d_out, int out_size, void* d_ws, size_t ws_size,
                              hipStream_t stream) {
  const float* x    = (const float*)d_in[0];
  const float* W_ih = (const float*)d_in[1];
  const float* W_hh = (const float*)d_in[2];
  const float* b_ih = (const float*)d_in[3];
  const float* b_hh = (const float*)d_in[4];
  const float* W_fc = (const float*)d_in[5];
  const float* b_fc = (const float*)d_in[6];
  float* out = (float*)d_out;

  dim3 grid(NBATCH / 16);   // 256 blocks x 16 batches; 4 waves = 4 unit-tiles
  dim3 block(256);
  gru_mfma_kernel<<<grid, block, 0, stream>>>(x, W_ih, W_hh, b_ih, b_hh, W_fc, b_fc, out);
}

// Round 8
// 248.725 us; speedup vs baseline: 1.8836x; 1.2134x over previous
//
#include <hip/hip_runtime.h>
#include <hip/hip_bf16.h>

#define T_LEN 512
#define HID 50
#define NBATCH 4096

using short8  = __attribute__((ext_vector_type(8))) short;
using floatx4 = __attribute__((ext_vector_type(4))) float;

__device__ __forceinline__ float sigm(float v) {
  return __builtin_amdgcn_rcpf(1.0f + __builtin_amdgcn_exp2f(-1.442695041f * v));
}
__device__ __forceinline__ float tanh_f(float v) {
  return 1.0f - 2.0f * __builtin_amdgcn_rcpf(1.0f + __builtin_amdgcn_exp2f(2.885390082f * v));
}

// h plane: 16 rows (m=batch) x 64 bf16 (u), row = 128 B, XOR swizzle ((row&7)<<4).
// k-bijection (same for A reads and B build): k = 32*f + 8*kg + e  (f=frag, e=0..7)
// -> A-fragment (f) = ONE contiguous 16B read at byte (64f + 16kg) ^ xr.
__device__ __forceinline__ short8 afrag(const char* plane, int rowoff, int off16) {
  return *(const short8*)(plane + rowoff + off16);
}

__global__ __launch_bounds__(256, 1)
void gru_mfma_kernel(const float* __restrict__ x,
                     const float* __restrict__ W_ih,
                     const float* __restrict__ W_hh,
                     const float* __restrict__ b_ih,
                     const float* __restrict__ b_hh,
                     const float* __restrict__ W_fc,
                     const float* __restrict__ b_fc,
                     float* __restrict__ out) {
  // LDS: [0,12288) x-chunk [t64][c3][m16] f32 ; [12288,14336) h buf0 ; [14336,16384) h buf1
  __shared__ alignas(16) unsigned char lds[16384];
  char* xs   = (char*)lds;
  char* hbuf = (char*)lds + 12288;

  const int tid  = threadIdx.x;
  const int lane = tid & 63;
  const int w    = tid >> 6;          // wave id: owns units 16w..16w+15
  const int ucol = lane & 15;         // N-col within tile / A-row (batch) index
  const int kg   = lane >> 4;         // k-group (slot) for A/B frags; m-group for C rows
  const int b0   = blockIdx.x * 16;
  const int u    = 16 * w + ucol;     // this lane's hidden unit
  const bool uv  = (u < HID);

  // ---- per-lane bias / input-weight constants ----
  const float c_r  = uv ? (b_ih[u] + b_hh[u]) : 0.f;
  const float c_z  = uv ? (b_ih[50 + u] + b_hh[50 + u]) : 0.f;
  const float c_ni = uv ? b_ih[100 + u] : 0.f;
  const float c_nh = uv ? b_hh[100 + u] : 0.f;
  float u_r[3], u_z[3], u_n[3];
#pragma unroll
  for (int c = 0; c < 3; ++c) {
    u_r[c] = uv ? W_ih[u * 3 + c] : 0.f;
    u_z[c] = uv ? W_ih[(50 + u) * 3 + c] : 0.f;
    u_n[c] = uv ? W_ih[(100 + u) * 3 + c] : 0.f;
  }
  const float wfc = uv ? W_fc[u] : 0.f;

  // ---- persistent B-fragments (W_hh), hi + lo split (term1 + term2) ----
  short8 Bh[3][2], Bl[3][2];
#pragma unroll
  for (int tau = 0; tau < 3; ++tau) {
    const int row = uv ? (tau * 50 + u) : 0;
    const float* Wrow = W_hh + row * HID;
#pragma unroll
    for (int f = 0; f < 2; ++f) {
      union { short a[8]; short8 s; } ph, pl;
#pragma unroll
      for (int e = 0; e < 8; ++e) {
        const int k = 32 * f + 8 * kg + e;          // NEW bijection (contiguous per slot)
        const float v = (uv && k < HID) ? Wrow[k] : 0.f;
        __hip_bfloat16 bh = __float2bfloat16(v);
        const float vh = __bfloat162float(bh);
        __hip_bfloat16 bl = __float2bfloat16(v - vh);
        ph.a[e] = *(short*)&bh;
        pl.a[e] = *(short*)&bl;
      }
      Bh[tau][f] = ph.s;
      Bl[tau][f] = pl.s;
    }
  }

  // zero both h planes (2 x 2048 B = 4096 B = 256 threads x 16 B)
  ((float4*)hbuf)[tid] = make_float4(0.f, 0.f, 0.f, 0.f);

  float h[4] = {0.f, 0.f, 0.f, 0.f};           // unit u, batches 4*kg..4*kg+3

  const int arow = ucol * 128;                  // A row offset (batch = ucol)
  const int axr  = (ucol & 7) << 4;             // A-read XOR
  const floatx4 z4 = {0.f, 0.f, 0.f, 0.f};

  for (int tc = 0; tc < 8; ++tc) {
    // ---- stage x chunk: 16 batches x 64 t x 3 c -> LDS [t][c][m] ----
    {
      const int sm = tid >> 4, seg = tid & 15;
      const float* xb = x + (size_t)(b0 + sm) * (T_LEN * 3) + tc * 192 + seg * 12;
      const float4 v0 = *(const float4*)(xb + 0);
      const float4 v1 = *(const float4*)(xb + 4);
      const float4 v2 = *(const float4*)(xb + 8);
      const float vv[12] = {v0.x, v0.y, v0.z, v0.w, v1.x, v1.y, v1.z, v1.w, v2.x, v2.y, v2.z, v2.w};
#pragma unroll
      for (int jj = 0; jj < 12; ++jj) {
        const int i = seg * 12 + jj;
        *(float*)(xs + (i / 3) * 192 + (i % 3) * 64 + sm * 4) = vv[jj];
      }
    }
    __syncthreads();

#pragma unroll 2
    for (int s = 0; s < 64; ++s) {
      const int par = s & 1;
      const char* rp = hbuf + par * 2048;
      char*       wp = hbuf + (par ^ 1) * 2048;

      // x reads (barrier-independent)
      const float4 xv0 = *(const float4*)(xs + s * 192 + 0 * 64 + kg * 16);
      const float4 xv1 = *(const float4*)(xs + s * 192 + 1 * 64 + kg * 16);
      const float4 xv2 = *(const float4*)(xs + s * 192 + 2 * 64 + kg * 16);

      // A-fragments: 2 x ds_read_b128, zero unpack
      const short8 A0 = afrag(rp, arow, (16 * kg +  0) ^ axr);
      const short8 A1 = afrag(rp, arow, (16 * kg + 64) ^ axr);

      // MFMA: term1 (A*Bh) + term2 (A*Bl), two 2-deep chains per gate
      floatx4 accA[3], accB[3];
#pragma unroll
      for (int tau = 0; tau < 3; ++tau) {
        floatx4 a = __builtin_amdgcn_mfma_f32_16x16x32_bf16(A0, Bh[tau][0], z4, 0, 0, 0);
        a = __builtin_amdgcn_mfma_f32_16x16x32_bf16(A1, Bh[tau][1], a, 0, 0, 0);
        accA[tau] = a;
        floatx4 b = __builtin_amdgcn_mfma_f32_16x16x32_bf16(A0, Bl[tau][0], z4, 0, 0, 0);
        b = __builtin_amdgcn_mfma_f32_16x16x32_bf16(A1, Bl[tau][1], b, 0, 0, 0);
        accB[tau] = b;
      }

      const float xa[4]  = {xv0.x, xv0.y, xv0.z, xv0.w};
      const float xb_[4] = {xv1.x, xv1.y, xv1.z, xv1.w};
      const float xc[4]  = {xv2.x, xv2.y, xv2.z, xv2.w};
#pragma unroll
      for (int r = 0; r < 4; ++r) {
        const float x0 = xa[r], x1 = xb_[r], x2 = xc[r];
        const float ar = accA[0][r] + accB[0][r];
        const float az = accA[1][r] + accB[1][r];
        const float an = accA[2][r] + accB[2][r];
        const float gr = fmaf(x0, u_r[0], fmaf(x1, u_r[1], fmaf(x2, u_r[2], c_r)));
        const float gz = fmaf(x0, u_z[0], fmaf(x1, u_z[1], fmaf(x2, u_z[2], c_z)));
        const float gn = fmaf(x0, u_n[0], fmaf(x1, u_n[1], fmaf(x2, u_n[2], c_ni)));
        const float rr = sigm(ar + gr);
        const float zz = sigm(az + gz);
        const float nv = gn + rr * (an + c_nh);
        const float nn = tanh_f(nv);
        const float hn = nn + zz * (h[r] - nn);
        h[r] = hn;
        // single bf16 store (hi only — term3 dropped)
        __hip_bfloat16 bh = __float2bfloat16(hn);
        const int mrow = 4 * kg + r;
        *(unsigned short*)(wp + mrow * 128 + ((2 * u) ^ ((mrow & 7) << 4))) =
            *(const unsigned short*)&bh;
      }
      __syncthreads();
    }
  }

  // ---- FC epilogue ----
  float p[4];
#pragma unroll
  for (int r = 0; r < 4; ++r) p[r] = h[r] * wfc;
#pragma unroll
  for (int mask = 1; mask < 16; mask <<= 1) {
#pragma unroll
    for (int r = 0; r < 4; ++r) p[r] += __shfl_xor(p[r], mask);
  }
  if (ucol == 0) {
    *(float4*)(lds + (w * 16 + 4 * kg) * 4) = make_float4(p[0], p[1], p[2], p[3]);
  }
  __syncthreads();
  if (tid < 16) {
    float ssum = 0.f;
#pragma unroll
    for (int ww = 0; ww < 4; ++ww) ssum += *(const float*)(lds + (ww * 16 + tid) * 4);
    out[b0 + tid] = ssum + b_fc[0];
  }
}

extern "C" void kernel_launch(void* const* d_in, const int* in_sizes, int n_in,
                              void* d_out, int out_size, void* d_ws, size_t ws_size,
                              hipStream_t stream) {
  const float* x    = (const float*)d_in[0];
  const float* W_ih = (const float*)d_in[1];
  const float* W_hh = (const float*)d_in[2];
  const float* b_ih = (const float*)d_in[3];
  const float* b_hh = (const float*)d_in[4];
  const float* W_fc = (const float*)d_in[5];
  const float* b_fc = (const float*)d_in[6];
  float* out = (float*)d_out;

  dim3 grid(NBATCH / 16);   // 256 blocks x 16 batches; 4 waves = 4 unit-tiles
  dim3 block(256);
  gru_mfma_kernel<<<grid, block, 0, stream>>>(x, W_ih, W_hh, b_ih, b_hh, W_fc, b_fc, out);
}